// Round 4
// baseline (302.936 us; speedup 1.0000x reference)
//
#include <hip/hip_runtime.h>
#include <hip/hip_bf16.h>

// Problem constants
constexpr int   kAtoms  = 5000;
constexpr int   kPairs  = 160000;
constexpr int   KD      = 128;   // K
constexpr int   NB      = 8;     // N_BASIS
constexpr int   RH      = 32;    // RAD_HIDDEN
constexpr float kCutoff = 5.0f;
constexpr float kPi     = 3.14159265358979323846f;
// INIT_SCALE * MSG_SCALE  (pass-1 l=0 message)
constexpr float C1 = 0.2f * 0.1767767f;
// (1 + INIT_SCALE) * MSG_SCALE (pass-2 l=0: sh0*Re0*inv + Re0*g == 1.2*Re0*G0[nbr])
constexpr float C2 = 1.2f * 0.1767767f;
constexpr int   PPB = 64;        // pairs per block in pair kernels

__device__ __forceinline__ float silu(float x) { return x / (1.0f + __expf(-x)); }

// Only the l=0 channel reaches the output (CG l=0 is o0 = v0 + v0^2*mix0,
// head reads only feats[0]); l=1/2, spherical harmonics, and U2 are dead code.
//   F0[a][k] = C1 * sum_{p: ctr=a} R0_p[k] * embed[spec[nbr_p]][k]
//   G0 = F0 + F0^2*mix0   (inline)
//   D0[a][k] = C2 * sum_{p: ctr=a} Re0_p[k] * G0[nbr_p][k]
//   h0 = (G0+D0) + (G0+D0)^2*emix0 ;  out = MLP(h0)   [out is fp32]

// ---------------------------------------------------------------------------
// Pair pass 1: F0 accumulation. 256 threads = 2 pair-lanes x 128 k.
// ---------------------------------------------------------------------------
__global__ __launch_bounds__(256) void pair_pass1(
    const float* __restrict__ pos, const float* __restrict__ cells,
    const int* __restrict__ species, const int* __restrict__ shifts,
    const int* __restrict__ ctr, const int* __restrict__ nbr,
    const int* __restrict__ spair,
    const float* __restrict__ embed,
    const float* __restrict__ w1, const float* __restrict__ b1,
    const float* __restrict__ w2, const float* __restrict__ b2,
    float* __restrict__ F0)
{
    __shared__ float s_rbf[PPB][NB];
    __shared__ float s_h[PPB][RH];
    __shared__ float s_w2[RH][KD];
    __shared__ int   s_ctr[PPB];
    __shared__ int   s_spec[PPB];

    int t = threadIdx.x;
    int k = t & 127;

    // stage the l=0 column block (RH x KD of the RH x 3KD matrix) into LDS
    for (int idx = t; idx < RH * KD; idx += 256)
        s_w2[idx >> 7][idx & 127] = w2[(idx >> 7) * (3 * KD) + (idx & 127)];

    float b2k = b2[k];
    float e0 = embed[0 * KD + k], e1 = embed[1 * KD + k];
    float e2 = embed[2 * KD + k], e3 = embed[3 * KD + k];

    // phase A: geometry -> rbf, one thread per pair
    if (t < PPB) {
        int p = blockIdx.x * PPB + t;
        int ci = ctr[p], ni = nbr[p], sp = spair[p];
        float s0 = (float)shifts[p * 3 + 0] - 1.0f;
        float s1 = (float)shifts[p * 3 + 1] - 1.0f;
        float s2 = (float)shifts[p * 3 + 2] - 1.0f;
        const float* C = cells + sp * 9;
        float vx = pos[ni * 3 + 0] - pos[ci * 3 + 0] + s0 * C[0] + s1 * C[3] + s2 * C[6];
        float vy = pos[ni * 3 + 1] - pos[ci * 3 + 1] + s0 * C[1] + s1 * C[4] + s2 * C[7];
        float vz = pos[ni * 3 + 2] - pos[ci * 3 + 2] + s0 * C[2] + s1 * C[5] + s2 * C[8];
        float d = sqrtf(vx * vx + vy * vy + vz * vz + 1e-12f);
        float fcut = (d < kCutoff) ? 0.5f * (__cosf(kPi * d / kCutoff) + 1.0f) : 0.0f;
        #pragma unroll
        for (int i = 0; i < NB; i++) {
            float tt = d - (kCutoff / (NB - 1)) * (float)i;
            s_rbf[t][i] = __expf(-2.0f * tt * tt) * fcut;
        }
        s_ctr[t]  = ci;
        s_spec[t] = species[ni];
    }
    __syncthreads();

    // phase B: hidden layer h = silu(rbf @ w1 + b1); 8 pairs x 32 j per sweep
    {
        int j   = t & 31;
        int prb = t >> 5;  // 0..7
        float b1j = b1[j];
        #pragma unroll
        for (int it = 0; it < PPB / 8; it++) {
            int pr = prb + it * 8;
            float acc = b1j;
            #pragma unroll
            for (int i = 0; i < NB; i++) acc += s_rbf[pr][i] * w1[i * RH + j];
            s_h[pr][j] = silu(acc);
        }
    }
    __syncthreads();

    // phase C: R0[k] and scatter
    int pl = t >> 7;  // pair lane 0/1
    for (int i = 0; i < PPB / 2; i++) {
        int pr = 2 * i + pl;
        float R0 = b2k;
        #pragma unroll
        for (int j = 0; j < RH; j++) R0 += s_h[pr][j] * s_w2[j][k];
        int s = s_spec[pr];
        float e = (s == 0) ? e0 : (s == 1) ? e1 : (s == 2) ? e2 : e3;
        atomicAdd(F0 + s_ctr[pr] * KD + k, C1 * R0 * e);
    }
}

// ---------------------------------------------------------------------------
// Pair pass 2: D0 accumulation (gathers G0[nbr] computed inline from F0).
// ---------------------------------------------------------------------------
__global__ __launch_bounds__(256) void pair_pass2(
    const float* __restrict__ pos, const float* __restrict__ cells,
    const int* __restrict__ shifts,
    const int* __restrict__ ctr, const int* __restrict__ nbr,
    const int* __restrict__ spair,
    const float* __restrict__ w1, const float* __restrict__ b1,
    const float* __restrict__ w2, const float* __restrict__ b2,
    const float* __restrict__ mix,   // mix_a row 0
    const float* __restrict__ F0,
    float* __restrict__ D0)
{
    __shared__ float s_rbf[PPB][NB];
    __shared__ float s_h[PPB][RH];
    __shared__ float s_w2[RH][KD];
    __shared__ int   s_ctr[PPB];
    __shared__ int   s_nbr[PPB];

    int t = threadIdx.x;
    int k = t & 127;

    for (int idx = t; idx < RH * KD; idx += 256)
        s_w2[idx >> 7][idx & 127] = w2[(idx >> 7) * (3 * KD) + (idx & 127)];

    float b2k  = b2[k];
    float mixk = mix[k];

    if (t < PPB) {
        int p = blockIdx.x * PPB + t;
        int ci = ctr[p], ni = nbr[p], sp = spair[p];
        float s0 = (float)shifts[p * 3 + 0] - 1.0f;
        float s1 = (float)shifts[p * 3 + 1] - 1.0f;
        float s2 = (float)shifts[p * 3 + 2] - 1.0f;
        const float* C = cells + sp * 9;
        float vx = pos[ni * 3 + 0] - pos[ci * 3 + 0] + s0 * C[0] + s1 * C[3] + s2 * C[6];
        float vy = pos[ni * 3 + 1] - pos[ci * 3 + 1] + s0 * C[1] + s1 * C[4] + s2 * C[7];
        float vz = pos[ni * 3 + 2] - pos[ci * 3 + 2] + s0 * C[2] + s1 * C[5] + s2 * C[8];
        float d = sqrtf(vx * vx + vy * vy + vz * vz + 1e-12f);
        float fcut = (d < kCutoff) ? 0.5f * (__cosf(kPi * d / kCutoff) + 1.0f) : 0.0f;
        #pragma unroll
        for (int i = 0; i < NB; i++) {
            float tt = d - (kCutoff / (NB - 1)) * (float)i;
            s_rbf[t][i] = __expf(-2.0f * tt * tt) * fcut;
        }
        s_ctr[t] = ci;
        s_nbr[t] = ni;
    }
    __syncthreads();

    {
        int j   = t & 31;
        int prb = t >> 5;
        float b1j = b1[j];
        #pragma unroll
        for (int it = 0; it < PPB / 8; it++) {
            int pr = prb + it * 8;
            float acc = b1j;
            #pragma unroll
            for (int i = 0; i < NB; i++) acc += s_rbf[pr][i] * w1[i * RH + j];
            s_h[pr][j] = silu(acc);
        }
    }
    __syncthreads();

    int pl = t >> 7;
    for (int i = 0; i < PPB / 2; i++) {
        int pr = 2 * i + pl;
        float R0 = b2k;
        #pragma unroll
        for (int j = 0; j < RH; j++) R0 += s_h[pr][j] * s_w2[j][k];
        float f = F0[s_nbr[pr] * KD + k];
        float g = f + f * f * mixk;   // G0 inline
        atomicAdd(D0 + s_ctr[pr] * KD + k, C2 * R0 * g);
    }
}

// ---------------------------------------------------------------------------
// Head: h0 = (G0+D0) + (G0+D0)^2*emix0; 2-layer MLP + final dot. 8 atoms/block.
// ---------------------------------------------------------------------------
__global__ __launch_bounds__(128) void head_kernel(
    const float* __restrict__ F0, const float* __restrict__ D0,
    const float* __restrict__ mix,  const float* __restrict__ emix,
    const float* __restrict__ w1, const float* __restrict__ b1,
    const float* __restrict__ w2, const float* __restrict__ b2,
    const float* __restrict__ lw, const float* __restrict__ lb,
    float* __restrict__ out)
{
    int j = threadIdx.x;
    __shared__ float s_v[KD];
    __shared__ float s_mid[KD];
    __shared__ float s_red[KD];

    float mixj  = mix[j];
    float emixj = emix[j];
    float b1j   = b1[j];
    float b2j   = b2[j];
    float lwj   = lw[j];
    float lb0   = lb[0];

    for (int a0 = 0; a0 < 8; a0++) {
        int a = blockIdx.x * 8 + a0;
        if (a >= kAtoms) break;  // uniform across block
        float f = F0[a * KD + j];
        float g = f + f * f * mixj;
        float n = g + D0[a * KD + j];
        s_v[j] = n + n * n * emixj;
        __syncthreads();

        float acc = b1j;
        #pragma unroll 8
        for (int kk = 0; kk < KD; kk++) acc += s_v[kk] * w1[kk * KD + j];
        s_mid[j] = silu(acc);
        __syncthreads();

        float acc2 = b2j;
        #pragma unroll 8
        for (int kk = 0; kk < KD; kk++) acc2 += s_mid[kk] * w2[kk * KD + j];
        s_red[j] = silu(acc2) * lwj;
        __syncthreads();

        #pragma unroll
        for (int s = 64; s > 0; s >>= 1) {
            if (j < s) s_red[j] += s_red[j + s];
            __syncthreads();
        }
        if (j == 0) out[a] = s_red[0] + lb0;
        __syncthreads();
    }
}

// ---------------------------------------------------------------------------
extern "C" void kernel_launch(void* const* d_in, const int* in_sizes, int n_in,
                              void* d_out, int out_size, void* d_ws, size_t ws_size,
                              hipStream_t stream) {
    const float* positions = (const float*)d_in[0];
    const float* cells     = (const float*)d_in[1];
    const int*   species   = (const int*)d_in[2];
    const int*   shifts    = (const int*)d_in[3];
    const int*   ctr       = (const int*)d_in[4];
    const int*   nbr       = (const int*)d_in[5];
    const int*   spair     = (const int*)d_in[6];
    const float* embed     = (const float*)d_in[7];
    const float* rad_w1    = (const float*)d_in[8];
    const float* rad_b1    = (const float*)d_in[9];
    const float* rad_w2    = (const float*)d_in[10];
    const float* rad_b2    = (const float*)d_in[11];
    const float* erad_w1   = (const float*)d_in[12];
    const float* erad_b1   = (const float*)d_in[13];
    const float* erad_w2   = (const float*)d_in[14];
    const float* erad_b2   = (const float*)d_in[15];
    const float* mix_a     = (const float*)d_in[16];
    const float* emix_a    = (const float*)d_in[17];
    const float* head_w1   = (const float*)d_in[18];
    const float* head_b1   = (const float*)d_in[19];
    const float* head_w2   = (const float*)d_in[20];
    const float* head_b2   = (const float*)d_in[21];
    const float* last_w    = (const float*)d_in[22];
    const float* last_b    = (const float*)d_in[23];
    // U2 (d_in[24]) is provably unused by the output (l>=1 channels are dead).

    float* F0 = (float*)d_ws;                       // 5000*128 fp32 = 2.56 MB
    float* D0 = F0 + (size_t)kAtoms * KD;           // 5000*128 fp32 = 2.56 MB
    size_t fbytes = (size_t)kAtoms * KD * sizeof(float);

    hipMemsetAsync(F0, 0, fbytes, stream);
    hipMemsetAsync(D0, 0, fbytes, stream);

    int pair_blocks = (kPairs + PPB - 1) / PPB;  // 2500

    pair_pass1<<<pair_blocks, 256, 0, stream>>>(
        positions, cells, species, shifts, ctr, nbr, spair,
        embed, rad_w1, rad_b1, rad_w2, rad_b2, F0);

    pair_pass2<<<pair_blocks, 256, 0, stream>>>(
        positions, cells, shifts, ctr, nbr, spair,
        erad_w1, erad_b1, erad_w2, erad_b2, mix_a, F0, D0);

    head_kernel<<<(kAtoms + 7) / 8, 128, 0, stream>>>(
        F0, D0, mix_a, emix_a,
        head_w1, head_b1, head_w2, head_b2, last_w, last_b,
        (float*)d_out);
}

// Round 5
// 299.202 us; speedup vs baseline: 1.0125x; 1.0125x over previous
//
#include <hip/hip_runtime.h>

// Problem constants
constexpr int   kAtoms  = 5000;
constexpr int   kPairs  = 160000;
constexpr int   KD      = 128;   // K
constexpr int   NB      = 8;     // N_BASIS
constexpr int   RH      = 32;    // RAD_HIDDEN
constexpr float kCutoff = 5.0f;
constexpr float kPi     = 3.14159265358979323846f;
// INIT_SCALE * MSG_SCALE  (pass-1 l=0 message)
constexpr float C1 = 0.2f * 0.1767767f;
// (1 + INIT_SCALE) * MSG_SCALE (pass-2 l=0 collapses to 1.2*Re0*G0[nbr])
constexpr float C2 = 1.2f * 0.1767767f;
constexpr int   CHUNK = 96;      // max pairs staged per atom-block iteration

__device__ __forceinline__ float silu(float x) { return x / (1.0f + __expf(-x)); }

// Only the l=0 channel reaches the output (CG l=0: o0 = v0 + v0^2*mix0 depends
// only on v0; head reads only feats[0]) — l>=1, spherical harmonics, U2 dead.
// Pipeline (CSR by center, NO float atomics):
//   K1 hist  : cnt[a] = #pairs with ctr==a
//   K2 scan  : off = exclusive_scan(cnt); cur = off
//   K3 build : per pair: rbf[8] -> sorted slot; store rbf, nbr, spec
//   K4 f0    : per atom: F0[k] = C1*sum_p R0_p[k]*e_spec[k]; G0 = F0+F0^2*mix
//   K5 d0    : per atom: D = sum_p Re0_p[k]*G0[nbr_p][k]; n = G0+C2*D;
//              V = n+n^2*emix
//   K6 head  : out = MLP(V) (register-tiled, 32 atoms/block)

// ---------------------------------------------------------------------------
__global__ __launch_bounds__(256) void hist_kernel(
    const int* __restrict__ ctr, int* __restrict__ cnt)
{
    int p = blockIdx.x * 256 + threadIdx.x;
    atomicAdd(cnt + ctr[p], 1);
}

// ---------------------------------------------------------------------------
__global__ __launch_bounds__(256) void scan_kernel(
    const int* __restrict__ cnt, int* __restrict__ off, int* __restrict__ cur)
{
    __shared__ int s_part[256];
    const int CH = 20;                      // 256*20 = 5120 >= 5000
    int t = threadIdx.x;
    int base = t * CH;
    int loc[CH];
    int run = 0;
    for (int i = 0; i < CH; i++) {
        int idx = base + i;
        int v = (idx < kAtoms) ? cnt[idx] : 0;
        loc[i] = run;
        run += v;
    }
    s_part[t] = run;
    __syncthreads();
    for (int st = 1; st < 256; st <<= 1) {
        int v = (t >= st) ? s_part[t - st] : 0;
        __syncthreads();
        s_part[t] += v;
        __syncthreads();
    }
    int excl = (t > 0) ? s_part[t - 1] : 0;
    for (int i = 0; i < CH; i++) {
        int idx = base + i;
        if (idx < kAtoms) { off[idx] = excl + loc[i]; cur[idx] = excl + loc[i]; }
    }
    if (t == 255) off[kAtoms] = s_part[255];
}

// ---------------------------------------------------------------------------
__global__ __launch_bounds__(256) void build_kernel(
    const float* __restrict__ pos, const float* __restrict__ cells,
    const int* __restrict__ species, const int* __restrict__ shifts,
    const int* __restrict__ ctr, const int* __restrict__ nbr,
    const int* __restrict__ spair,
    int* __restrict__ cur, int* __restrict__ nbrs_s, int* __restrict__ specs_s,
    float* __restrict__ rbf_s)
{
    int p = blockIdx.x * 256 + threadIdx.x;
    int ci = ctr[p], ni = nbr[p], sp = spair[p];
    float s0 = (float)shifts[p * 3 + 0] - 1.0f;
    float s1 = (float)shifts[p * 3 + 1] - 1.0f;
    float s2 = (float)shifts[p * 3 + 2] - 1.0f;
    const float* C = cells + sp * 9;
    float vx = pos[ni * 3 + 0] - pos[ci * 3 + 0] + s0 * C[0] + s1 * C[3] + s2 * C[6];
    float vy = pos[ni * 3 + 1] - pos[ci * 3 + 1] + s0 * C[1] + s1 * C[4] + s2 * C[7];
    float vz = pos[ni * 3 + 2] - pos[ci * 3 + 2] + s0 * C[2] + s1 * C[5] + s2 * C[8];
    float d = sqrtf(vx * vx + vy * vy + vz * vz + 1e-12f);
    float fcut = (d < kCutoff) ? 0.5f * (__cosf(kPi * d / kCutoff) + 1.0f) : 0.0f;

    int slot = atomicAdd(cur + ci, 1);
    nbrs_s[slot]  = ni;
    specs_s[slot] = species[ni];

    float r[NB];
    #pragma unroll
    for (int i = 0; i < NB; i++) {
        float tt = d - (kCutoff / (NB - 1)) * (float)i;
        r[i] = __expf(-2.0f * tt * tt) * fcut;
    }
    float4* dst = (float4*)(rbf_s + (size_t)slot * NB);
    dst[0] = make_float4(r[0], r[1], r[2], r[3]);
    dst[1] = make_float4(r[4], r[5], r[6], r[7]);
}

// ---------------------------------------------------------------------------
// K4: per-atom F0 accumulation + G0 store. 128 threads (k), 1 atom per block.
// ---------------------------------------------------------------------------
__global__ __launch_bounds__(128) void f0_kernel(
    const float* __restrict__ rbf_s, const int* __restrict__ specs_s,
    const int* __restrict__ off,
    const float* __restrict__ embed,
    const float* __restrict__ w1, const float* __restrict__ b1,
    const float* __restrict__ w2, const float* __restrict__ b2,
    const float* __restrict__ mix,
    float* __restrict__ G0)
{
    __shared__ float  s_w1[NB][RH];
    __shared__ float  s_b1[RH];
    __shared__ float4 s_h4[CHUNK][RH / 4];
    __shared__ int    s_spec[CHUNK];

    int t = threadIdx.x, k = t;
    for (int idx = t; idx < NB * RH; idx += 128)
        s_w1[idx >> 5][idx & 31] = w1[idx];
    if (t < RH) s_b1[t] = b1[t];

    int a = blockIdx.x;
    int start = off[a], end = off[a + 1];

    float w2col[RH];
    #pragma unroll
    for (int j = 0; j < RH; j++) w2col[j] = w2[j * (3 * KD) + k];
    float e0 = embed[0 * KD + k], e1 = embed[1 * KD + k];
    float e2 = embed[2 * KD + k], e3 = embed[3 * KD + k];
    float b2k = b2[k];

    float F = 0.0f;
    for (int c = start; c < end; c += CHUNK) {
        int m = min(CHUNK, end - c);
        __syncthreads();
        {   // hidden layer for this chunk: 4 pair-rows in parallel (j = t&31)
            int j = t & 31, g = t >> 5;
            for (int pr = g; pr < m; pr += 4) {
                const float* rb = rbf_s + (size_t)(c + pr) * NB;
                float acc = s_b1[j];
                #pragma unroll
                for (int i = 0; i < NB; i++) acc += rb[i] * s_w1[i][j];
                ((float*)&s_h4[pr][0])[j] = silu(acc);
            }
            for (int i = t; i < m; i += 128) s_spec[i] = specs_s[c + i];
        }
        __syncthreads();
        for (int i = 0; i < m; i++) {
            float Ra = b2k, Rb = 0.0f;
            #pragma unroll
            for (int jq = 0; jq < RH / 4; jq += 2) {
                float4 ha = s_h4[i][jq];
                float4 hb = s_h4[i][jq + 1];
                Ra += ha.x * w2col[4 * jq + 0] + ha.y * w2col[4 * jq + 1]
                    + ha.z * w2col[4 * jq + 2] + ha.w * w2col[4 * jq + 3];
                Rb += hb.x * w2col[4 * jq + 4] + hb.y * w2col[4 * jq + 5]
                    + hb.z * w2col[4 * jq + 6] + hb.w * w2col[4 * jq + 7];
            }
            int s = s_spec[i];
            float e = (s == 0) ? e0 : (s == 1) ? e1 : (s == 2) ? e2 : e3;
            F += (Ra + Rb) * e;
        }
    }
    float F0v = C1 * F;
    G0[(size_t)a * KD + k] = F0v + F0v * F0v * mix[k];
}

// ---------------------------------------------------------------------------
// K5: per-atom D0 accumulation (gather G0[nbr]) + head-input V store.
// ---------------------------------------------------------------------------
__global__ __launch_bounds__(128) void d0_kernel(
    const float* __restrict__ rbf_s, const int* __restrict__ nbrs_s,
    const int* __restrict__ off,
    const float* __restrict__ w1, const float* __restrict__ b1,
    const float* __restrict__ w2, const float* __restrict__ b2,
    const float* __restrict__ emix,
    const float* __restrict__ G0,
    float* __restrict__ V)
{
    __shared__ float  s_w1[NB][RH];
    __shared__ float  s_b1[RH];
    __shared__ float4 s_h4[CHUNK][RH / 4];
    __shared__ int    s_nbr[CHUNK];

    int t = threadIdx.x, k = t;
    for (int idx = t; idx < NB * RH; idx += 128)
        s_w1[idx >> 5][idx & 31] = w1[idx];
    if (t < RH) s_b1[t] = b1[t];

    int a = blockIdx.x;
    int start = off[a], end = off[a + 1];

    float w2col[RH];
    #pragma unroll
    for (int j = 0; j < RH; j++) w2col[j] = w2[j * (3 * KD) + k];
    float b2k = b2[k];

    float D = 0.0f;
    for (int c = start; c < end; c += CHUNK) {
        int m = min(CHUNK, end - c);
        __syncthreads();
        {
            int j = t & 31, g = t >> 5;
            for (int pr = g; pr < m; pr += 4) {
                const float* rb = rbf_s + (size_t)(c + pr) * NB;
                float acc = s_b1[j];
                #pragma unroll
                for (int i = 0; i < NB; i++) acc += rb[i] * s_w1[i][j];
                ((float*)&s_h4[pr][0])[j] = silu(acc);
            }
            for (int i = t; i < m; i += 128) s_nbr[i] = nbrs_s[c + i];
        }
        __syncthreads();
        for (int i = 0; i < m; i++) {
            float gv = G0[(size_t)s_nbr[i] * KD + k];   // issue gather early
            float Ra = b2k, Rb = 0.0f;
            #pragma unroll
            for (int jq = 0; jq < RH / 4; jq += 2) {
                float4 ha = s_h4[i][jq];
                float4 hb = s_h4[i][jq + 1];
                Ra += ha.x * w2col[4 * jq + 0] + ha.y * w2col[4 * jq + 1]
                    + ha.z * w2col[4 * jq + 2] + ha.w * w2col[4 * jq + 3];
                Rb += hb.x * w2col[4 * jq + 4] + hb.y * w2col[4 * jq + 5]
                    + hb.z * w2col[4 * jq + 6] + hb.w * w2col[4 * jq + 7];
            }
            D += (Ra + Rb) * gv;
        }
    }
    float n = G0[(size_t)a * KD + k] + C2 * D;
    V[(size_t)a * KD + k] = n + n * n * emix[k];
}

// ---------------------------------------------------------------------------
// K6: head MLP, 32 atoms per block, register-tiled (weights read once/block).
// ---------------------------------------------------------------------------
__global__ __launch_bounds__(128) void head_kernel(
    const float* __restrict__ V,
    const float* __restrict__ w1, const float* __restrict__ b1,
    const float* __restrict__ w2, const float* __restrict__ b2,
    const float* __restrict__ lw, const float* __restrict__ lb,
    float* __restrict__ out)
{
    __shared__ float s_a[32][KD];
    __shared__ float s_b[32][KD];
    int j = threadIdx.x;
    int abase = blockIdx.x * 32;

    for (int a = 0; a < 32; a++) {
        int ga = abase + a;
        s_a[a][j] = (ga < kAtoms) ? V[(size_t)ga * KD + j] : 0.0f;
    }
    __syncthreads();

    float acc[32];
    float bj = b1[j];
    #pragma unroll
    for (int a = 0; a < 32; a++) acc[a] = bj;
    for (int kk = 0; kk < KD; kk += 4) {
        float wa = w1[(kk + 0) * KD + j], wb = w1[(kk + 1) * KD + j];
        float wc = w1[(kk + 2) * KD + j], wd = w1[(kk + 3) * KD + j];
        #pragma unroll
        for (int a = 0; a < 32; a++) {
            float4 v = *(const float4*)&s_a[a][kk];
            acc[a] += v.x * wa + v.y * wb + v.z * wc + v.w * wd;
        }
    }
    for (int a = 0; a < 32; a++) s_b[a][j] = silu(acc[a]);
    __syncthreads();

    float b2j = b2[j];
    #pragma unroll
    for (int a = 0; a < 32; a++) acc[a] = b2j;
    for (int kk = 0; kk < KD; kk += 4) {
        float wa = w2[(kk + 0) * KD + j], wb = w2[(kk + 1) * KD + j];
        float wc = w2[(kk + 2) * KD + j], wd = w2[(kk + 3) * KD + j];
        #pragma unroll
        for (int a = 0; a < 32; a++) {
            float4 v = *(const float4*)&s_b[a][kk];
            acc[a] += v.x * wa + v.y * wb + v.z * wc + v.w * wd;
        }
    }
    float lwj = lw[j];
    __syncthreads();
    for (int a = 0; a < 32; a++) s_a[a][j] = silu(acc[a]) * lwj;
    __syncthreads();
    for (int s = 64; s > 0; s >>= 1) {
        if (j < s) {
            for (int a = 0; a < 32; a++) s_a[a][j] += s_a[a][j + s];
        }
        __syncthreads();
    }
    if (j < 32) {
        int ga = abase + j;
        if (ga < kAtoms) out[ga] = s_a[j][0] + lb[0];
    }
}

// ---------------------------------------------------------------------------
extern "C" void kernel_launch(void* const* d_in, const int* in_sizes, int n_in,
                              void* d_out, int out_size, void* d_ws, size_t ws_size,
                              hipStream_t stream) {
    const float* positions = (const float*)d_in[0];
    const float* cells     = (const float*)d_in[1];
    const int*   species   = (const int*)d_in[2];
    const int*   shifts    = (const int*)d_in[3];
    const int*   ctr       = (const int*)d_in[4];
    const int*   nbr       = (const int*)d_in[5];
    const int*   spair     = (const int*)d_in[6];
    const float* embed     = (const float*)d_in[7];
    const float* rad_w1    = (const float*)d_in[8];
    const float* rad_b1    = (const float*)d_in[9];
    const float* rad_w2    = (const float*)d_in[10];
    const float* rad_b2    = (const float*)d_in[11];
    const float* erad_w1   = (const float*)d_in[12];
    const float* erad_b1   = (const float*)d_in[13];
    const float* erad_w2   = (const float*)d_in[14];
    const float* erad_b2   = (const float*)d_in[15];
    const float* mix_a     = (const float*)d_in[16];
    const float* emix_a    = (const float*)d_in[17];
    const float* head_w1   = (const float*)d_in[18];
    const float* head_b1   = (const float*)d_in[19];
    const float* head_w2   = (const float*)d_in[20];
    const float* head_b2   = (const float*)d_in[21];
    const float* last_w    = (const float*)d_in[22];
    const float* last_b    = (const float*)d_in[23];
    // U2 (d_in[24]) unused: l>=1 channels are dead code for the output.

    // Workspace layout (floats first for 16B alignment of float4 stores)
    float* rbf_s = (float*)d_ws;                          // 160000*8
    float* G0    = rbf_s + (size_t)kPairs * NB;           // 5000*128
    float* V     = G0    + (size_t)kAtoms * KD;           // 5000*128
    int*   cnt   = (int*)(V + (size_t)kAtoms * KD);       // 5000
    int*   off   = cnt + kAtoms;                          // 5001
    int*   cur   = off + kAtoms + 1;                      // 5000
    int*   nbrs  = cur + kAtoms;                          // 160000
    int*   specs = nbrs + kPairs;                         // 160000
    // total ~= 11.6 MB

    hipMemsetAsync(cnt, 0, kAtoms * sizeof(int), stream);

    hist_kernel<<<kPairs / 256, 256, 0, stream>>>(ctr, cnt);
    scan_kernel<<<1, 256, 0, stream>>>(cnt, off, cur);
    build_kernel<<<kPairs / 256, 256, 0, stream>>>(
        positions, cells, species, shifts, ctr, nbr, spair,
        cur, nbrs, specs, rbf_s);

    f0_kernel<<<kAtoms, 128, 0, stream>>>(
        rbf_s, specs, off, embed, rad_w1, rad_b1, rad_w2, rad_b2,
        mix_a, G0);

    d0_kernel<<<kAtoms, 128, 0, stream>>>(
        rbf_s, nbrs, off, erad_w1, erad_b1, erad_w2, erad_b2,
        emix_a, G0, V);

    head_kernel<<<(kAtoms + 31) / 32, 128, 0, stream>>>(
        V, head_w1, head_b1, head_w2, head_b2, last_w, last_b,
        (float*)d_out);
}

// Round 6
// 222.128 us; speedup vs baseline: 1.3638x; 1.3470x over previous
//
#include <hip/hip_runtime.h>

// Problem constants
constexpr int   kAtoms  = 5000;
constexpr int   kPairs  = 160000;
constexpr int   KD      = 128;   // K
constexpr int   NB      = 8;     // N_BASIS
constexpr int   RH      = 32;    // RAD_HIDDEN
constexpr float kCutoff = 5.0f;
constexpr float kPi     = 3.14159265358979323846f;
constexpr float C1 = 0.2f * 0.1767767f;   // INIT_SCALE * MSG_SCALE
constexpr float C2 = 1.2f * 0.1767767f;   // (1+INIT_SCALE) * MSG_SCALE
constexpr int   CHUNK = 96;

__device__ __forceinline__ float silu(float x) { return x / (1.0f + __expf(-x)); }

// Only the l=0 channel reaches the output; l>=1 / sph / U2 are dead code.
//   F0[a][k] = C1 * sum_p R0_p[k]*e_spec[k];  G0 = F0+F0^2*mix
//   D[a][k]  = sum_p Re0_p[k]*G0[nbr_p][k];   n = G0+C2*D;  V = n+n^2*emix
//   out = head MLP(V)
// f0 uses species factoring:
//   F0[a][k] = C1*( b2[k]*sum_s n_s*e_s[k] + sum_s e_s[k]*sum_j w2[j][k]*H_s[j] )
//   with H_s[j] = sum_{p in s} h_p[j]   (no per-pair k loop at all)

// ---------------------------------------------------------------------------
__global__ __launch_bounds__(256) void hist_kernel(
    const int* __restrict__ ctr, int* __restrict__ cnt)
{
    int p = blockIdx.x * 256 + threadIdx.x;
    atomicAdd(cnt + ctr[p], 1);
}

// ---------------------------------------------------------------------------
__global__ __launch_bounds__(1024) void scan_kernel(
    const int* __restrict__ cnt, int* __restrict__ off, int* __restrict__ cur)
{
    __shared__ int s_part[1024];
    const int CH = 5;                       // 1024*5 = 5120 >= 5000
    int t = threadIdx.x;
    int base = t * CH;
    int loc[CH];
    int run = 0;
    #pragma unroll
    for (int i = 0; i < CH; i++) {
        int idx = base + i;
        int v = (idx < kAtoms) ? cnt[idx] : 0;
        loc[i] = run;
        run += v;
    }
    s_part[t] = run;
    __syncthreads();
    for (int st = 1; st < 1024; st <<= 1) {
        int v = (t >= st) ? s_part[t - st] : 0;
        __syncthreads();
        s_part[t] += v;
        __syncthreads();
    }
    int excl = (t > 0) ? s_part[t - 1] : 0;
    #pragma unroll
    for (int i = 0; i < CH; i++) {
        int idx = base + i;
        if (idx < kAtoms) { off[idx] = excl + loc[i]; cur[idx] = excl + loc[i]; }
    }
    if (t == 1023) off[kAtoms] = s_part[1023];
}

// ---------------------------------------------------------------------------
__global__ __launch_bounds__(256) void build_kernel(
    const float* __restrict__ pos, const float* __restrict__ cells,
    const int* __restrict__ species, const int* __restrict__ shifts,
    const int* __restrict__ ctr, const int* __restrict__ nbr,
    const int* __restrict__ spair,
    int* __restrict__ cur, int* __restrict__ nbrs_s, int* __restrict__ specs_s,
    float* __restrict__ rbf_s)
{
    int p = blockIdx.x * 256 + threadIdx.x;
    int ci = ctr[p], ni = nbr[p], sp = spair[p];
    float s0 = (float)shifts[p * 3 + 0] - 1.0f;
    float s1 = (float)shifts[p * 3 + 1] - 1.0f;
    float s2 = (float)shifts[p * 3 + 2] - 1.0f;
    const float* C = cells + sp * 9;
    float vx = pos[ni * 3 + 0] - pos[ci * 3 + 0] + s0 * C[0] + s1 * C[3] + s2 * C[6];
    float vy = pos[ni * 3 + 1] - pos[ci * 3 + 1] + s0 * C[1] + s1 * C[4] + s2 * C[7];
    float vz = pos[ni * 3 + 2] - pos[ci * 3 + 2] + s0 * C[2] + s1 * C[5] + s2 * C[8];
    float d = sqrtf(vx * vx + vy * vy + vz * vz + 1e-12f);
    float fcut = (d < kCutoff) ? 0.5f * (__cosf(kPi * d / kCutoff) + 1.0f) : 0.0f;

    int slot = atomicAdd(cur + ci, 1);
    nbrs_s[slot]  = ni;
    specs_s[slot] = species[ni];

    float r[NB];
    #pragma unroll
    for (int i = 0; i < NB; i++) {
        float tt = d - (kCutoff / (NB - 1)) * (float)i;
        r[i] = __expf(-2.0f * tt * tt) * fcut;
    }
    float4* dst = (float4*)(rbf_s + (size_t)slot * NB);
    dst[0] = make_float4(r[0], r[1], r[2], r[3]);
    dst[1] = make_float4(r[4], r[5], r[6], r[7]);
}

// ---------------------------------------------------------------------------
// K4: species-factored F0 + G0 store. 64 threads (1 wave) per atom.
// ---------------------------------------------------------------------------
__global__ __launch_bounds__(64) void f0_kernel(
    const float* __restrict__ rbf_s, const int* __restrict__ specs_s,
    const int* __restrict__ off,
    const float* __restrict__ embed,
    const float* __restrict__ w1, const float* __restrict__ b1,
    const float* __restrict__ w2, const float* __restrict__ b2,
    const float* __restrict__ mix,
    float* __restrict__ G0)
{
    __shared__ float s_w1[NB][RH];
    __shared__ float s_b1v[RH];
    __shared__ float s_Hp[2][4][RH];
    __shared__ float s_H[4][RH];
    __shared__ float s_np[2][4];
    __shared__ float s_nc[4];

    int t = threadIdx.x;
    for (int idx = t; idx < NB * RH; idx += 64)
        s_w1[idx >> 5][idx & 31] = w1[idx];
    if (t < RH) s_b1v[t] = b1[t];
    __syncthreads();

    int a = blockIdx.x;
    int start = off[a], m = off[a + 1] - start;

    int g = t >> 5, j = t & 31;
    float H0 = 0, H1 = 0, H2 = 0, H3 = 0;
    int   n0 = 0, n1 = 0, n2 = 0, n3 = 0;
    float b1j = s_b1v[j];
    for (int pr = g; pr < m; pr += 2) {
        const float* rb = rbf_s + (size_t)(start + pr) * NB;
        float acc = b1j;
        #pragma unroll
        for (int i = 0; i < NB; i++) acc += rb[i] * s_w1[i][j];
        float h = silu(acc);
        int s = specs_s[start + pr];
        H0 += (s == 0) ? h : 0.0f;  H1 += (s == 1) ? h : 0.0f;
        H2 += (s == 2) ? h : 0.0f;  H3 += (s == 3) ? h : 0.0f;
        n0 += (s == 0); n1 += (s == 1); n2 += (s == 2); n3 += (s == 3);
    }
    s_Hp[g][0][j] = H0; s_Hp[g][1][j] = H1;
    s_Hp[g][2][j] = H2; s_Hp[g][3][j] = H3;
    if (j == 0) {
        s_np[g][0] = (float)n0; s_np[g][1] = (float)n1;
        s_np[g][2] = (float)n2; s_np[g][3] = (float)n3;
    }
    __syncthreads();
    for (int e = t; e < 4 * RH; e += 64) {
        int s = e >> 5, jj = e & 31;
        s_H[s][jj] = s_Hp[0][s][jj] + s_Hp[1][s][jj];
    }
    if (t < 4) s_nc[t] = s_np[0][t] + s_np[1][t];
    __syncthreads();

    float nc0 = s_nc[0], nc1 = s_nc[1], nc2 = s_nc[2], nc3 = s_nc[3];
    #pragma unroll
    for (int half = 0; half < 2; half++) {
        int k = t + 64 * half;
        float e0 = embed[0 * KD + k], e1 = embed[1 * KD + k];
        float e2 = embed[2 * KD + k], e3 = embed[3 * KD + k];
        float P0 = 0, P1 = 0, P2 = 0, P3 = 0;
        #pragma unroll 2
        for (int jq = 0; jq < RH / 4; jq++) {
            float4 h0 = *(const float4*)&s_H[0][4 * jq];
            float4 h1 = *(const float4*)&s_H[1][4 * jq];
            float4 h2 = *(const float4*)&s_H[2][4 * jq];
            float4 h3 = *(const float4*)&s_H[3][4 * jq];
            float wa = w2[(4 * jq + 0) * (3 * KD) + k];
            float wb = w2[(4 * jq + 1) * (3 * KD) + k];
            float wc = w2[(4 * jq + 2) * (3 * KD) + k];
            float wd = w2[(4 * jq + 3) * (3 * KD) + k];
            P0 += h0.x * wa + h0.y * wb + h0.z * wc + h0.w * wd;
            P1 += h1.x * wa + h1.y * wb + h1.z * wc + h1.w * wd;
            P2 += h2.x * wa + h2.y * wb + h2.z * wc + h2.w * wd;
            P3 += h3.x * wa + h3.y * wb + h3.z * wc + h3.w * wd;
        }
        float F = b2[k] * (nc0 * e0 + nc1 * e1 + nc2 * e2 + nc3 * e3)
                + e0 * P0 + e1 * P1 + e2 * P2 + e3 * P3;
        float F0v = C1 * F;
        G0[(size_t)a * KD + k] = F0v + F0v * F0v * mix[k];
    }
}

// ---------------------------------------------------------------------------
// K5: D0 + V. 64 threads (1 wave) per atom; each lane handles k and k+64.
// ---------------------------------------------------------------------------
__global__ __launch_bounds__(64) void d0_kernel(
    const float* __restrict__ rbf_s, const int* __restrict__ nbrs_s,
    const int* __restrict__ off,
    const float* __restrict__ w1, const float* __restrict__ b1,
    const float* __restrict__ w2, const float* __restrict__ b2,
    const float* __restrict__ emix,
    const float* __restrict__ G0,
    float* __restrict__ V)
{
    __shared__ float s_w1[NB][RH];
    __shared__ float s_b1v[RH];
    __shared__ float s_h[CHUNK][RH];
    __shared__ int   s_nbr[CHUNK];

    int t = threadIdx.x;
    for (int idx = t; idx < NB * RH; idx += 64)
        s_w1[idx >> 5][idx & 31] = w1[idx];
    if (t < RH) s_b1v[t] = b1[t];

    int a = blockIdx.x;
    int start = off[a], end = off[a + 1];
    int k0 = t, k1 = t + 64;

    float w2c0[RH], w2c1[RH];
    #pragma unroll
    for (int j = 0; j < RH; j++) {
        w2c0[j] = w2[j * (3 * KD) + k0];
        w2c1[j] = w2[j * (3 * KD) + k1];
    }
    float b2k0 = b2[k0], b2k1 = b2[k1];

    int g = t >> 5, j = t & 31;
    float b1j = s_b1v[j];

    float Dacc0 = 0.0f, Dacc1 = 0.0f;
    for (int c = start; c < end; c += CHUNK) {
        int m = min(CHUNK, end - c);
        __syncthreads();
        for (int pr = g; pr < m; pr += 2) {
            const float* rb = rbf_s + (size_t)(c + pr) * NB;
            float acc = b1j;
            #pragma unroll
            for (int i = 0; i < NB; i++) acc += rb[i] * s_w1[i][j];
            s_h[pr][j] = silu(acc);
        }
        for (int i = t; i < m; i += 64) s_nbr[i] = nbrs_s[c + i];
        __syncthreads();
        for (int i = 0; i < m; i++) {
            const float* gbase = G0 + (size_t)s_nbr[i] * KD;
            float gv0 = gbase[k0];
            float gv1 = gbase[k1];
            float R0 = b2k0, R1 = b2k1;
            #pragma unroll
            for (int jq = 0; jq < RH / 4; jq++) {
                float4 h4 = *(const float4*)&s_h[i][4 * jq];
                R0 += h4.x * w2c0[4 * jq + 0] + h4.y * w2c0[4 * jq + 1]
                    + h4.z * w2c0[4 * jq + 2] + h4.w * w2c0[4 * jq + 3];
                R1 += h4.x * w2c1[4 * jq + 0] + h4.y * w2c1[4 * jq + 1]
                    + h4.z * w2c1[4 * jq + 2] + h4.w * w2c1[4 * jq + 3];
            }
            Dacc0 += R0 * gv0;
            Dacc1 += R1 * gv1;
        }
    }
    float n0 = G0[(size_t)a * KD + k0] + C2 * Dacc0;
    float n1 = G0[(size_t)a * KD + k1] + C2 * Dacc1;
    V[(size_t)a * KD + k0] = n0 + n0 * n0 * emix[k0];
    V[(size_t)a * KD + k1] = n1 + n1 * n1 * emix[k1];
}

// ---------------------------------------------------------------------------
// K6: head MLP, 8 atoms per block (625 blocks for occupancy).
// ---------------------------------------------------------------------------
__global__ __launch_bounds__(128) void head_kernel(
    const float* __restrict__ V,
    const float* __restrict__ w1, const float* __restrict__ b1,
    const float* __restrict__ w2, const float* __restrict__ b2,
    const float* __restrict__ lw, const float* __restrict__ lb,
    float* __restrict__ out)
{
    __shared__ float s_a[8][KD];
    __shared__ float s_b[8][KD];
    int j = threadIdx.x;
    int abase = blockIdx.x * 8;

    #pragma unroll
    for (int a = 0; a < 8; a++) {
        int ga = abase + a;
        s_a[a][j] = (ga < kAtoms) ? V[(size_t)ga * KD + j] : 0.0f;
    }
    __syncthreads();

    float acc[8];
    float bj = b1[j];
    #pragma unroll
    for (int a = 0; a < 8; a++) acc[a] = bj;
    for (int kk = 0; kk < KD; kk += 4) {
        float wa = w1[(kk + 0) * KD + j], wb = w1[(kk + 1) * KD + j];
        float wc = w1[(kk + 2) * KD + j], wd = w1[(kk + 3) * KD + j];
        #pragma unroll
        for (int a = 0; a < 8; a++) {
            float4 v = *(const float4*)&s_a[a][kk];
            acc[a] += v.x * wa + v.y * wb + v.z * wc + v.w * wd;
        }
    }
    #pragma unroll
    for (int a = 0; a < 8; a++) s_b[a][j] = silu(acc[a]);
    __syncthreads();

    float b2j = b2[j];
    #pragma unroll
    for (int a = 0; a < 8; a++) acc[a] = b2j;
    for (int kk = 0; kk < KD; kk += 4) {
        float wa = w2[(kk + 0) * KD + j], wb = w2[(kk + 1) * KD + j];
        float wc = w2[(kk + 2) * KD + j], wd = w2[(kk + 3) * KD + j];
        #pragma unroll
        for (int a = 0; a < 8; a++) {
            float4 v = *(const float4*)&s_b[a][kk];
            acc[a] += v.x * wa + v.y * wb + v.z * wc + v.w * wd;
        }
    }
    float lwj = lw[j];
    __syncthreads();
    #pragma unroll
    for (int a = 0; a < 8; a++) s_a[a][j] = silu(acc[a]) * lwj;
    __syncthreads();
    for (int s = 64; s > 0; s >>= 1) {
        if (j < s) {
            #pragma unroll
            for (int a = 0; a < 8; a++) s_a[a][j] += s_a[a][j + s];
        }
        __syncthreads();
    }
    if (j < 8) {
        int ga = abase + j;
        if (ga < kAtoms) out[ga] = s_a[j][0] + lb[0];
    }
}

// ---------------------------------------------------------------------------
extern "C" void kernel_launch(void* const* d_in, const int* in_sizes, int n_in,
                              void* d_out, int out_size, void* d_ws, size_t ws_size,
                              hipStream_t stream) {
    const float* positions = (const float*)d_in[0];
    const float* cells     = (const float*)d_in[1];
    const int*   species   = (const int*)d_in[2];
    const int*   shifts    = (const int*)d_in[3];
    const int*   ctr       = (const int*)d_in[4];
    const int*   nbr       = (const int*)d_in[5];
    const int*   spair     = (const int*)d_in[6];
    const float* embed     = (const float*)d_in[7];
    const float* rad_w1    = (const float*)d_in[8];
    const float* rad_b1    = (const float*)d_in[9];
    const float* rad_w2    = (const float*)d_in[10];
    const float* rad_b2    = (const float*)d_in[11];
    const float* erad_w1   = (const float*)d_in[12];
    const float* erad_b1   = (const float*)d_in[13];
    const float* erad_w2   = (const float*)d_in[14];
    const float* erad_b2   = (const float*)d_in[15];
    const float* mix_a     = (const float*)d_in[16];
    const float* emix_a    = (const float*)d_in[17];
    const float* head_w1   = (const float*)d_in[18];
    const float* head_b1   = (const float*)d_in[19];
    const float* head_w2   = (const float*)d_in[20];
    const float* head_b2   = (const float*)d_in[21];
    const float* last_w    = (const float*)d_in[22];
    const float* last_b    = (const float*)d_in[23];
    // U2 (d_in[24]) unused: l>=1 channels are dead code for the output.

    float* rbf_s = (float*)d_ws;                          // 160000*8
    float* G0    = rbf_s + (size_t)kPairs * NB;           // 5000*128
    float* V     = G0    + (size_t)kAtoms * KD;           // 5000*128
    int*   cnt   = (int*)(V + (size_t)kAtoms * KD);       // 5000
    int*   off   = cnt + kAtoms;                          // 5001
    int*   cur   = off + kAtoms + 1;                      // 5000
    int*   nbrs  = cur + kAtoms;                          // 160000
    int*   specs = nbrs + kPairs;                         // 160000

    hipMemsetAsync(cnt, 0, kAtoms * sizeof(int), stream);

    hist_kernel<<<kPairs / 256, 256, 0, stream>>>(ctr, cnt);
    scan_kernel<<<1, 1024, 0, stream>>>(cnt, off, cur);
    build_kernel<<<kPairs / 256, 256, 0, stream>>>(
        positions, cells, species, shifts, ctr, nbr, spair,
        cur, nbrs, specs, rbf_s);

    f0_kernel<<<kAtoms, 64, 0, stream>>>(
        rbf_s, specs, off, embed, rad_w1, rad_b1, rad_w2, rad_b2,
        mix_a, G0);

    d0_kernel<<<kAtoms, 64, 0, stream>>>(
        rbf_s, nbrs, off, erad_w1, erad_b1, erad_w2, erad_b2,
        emix_a, G0, V);

    head_kernel<<<(kAtoms + 7) / 8, 128, 0, stream>>>(
        V, head_w1, head_b1, head_w2, head_b2, last_w, last_b,
        (float*)d_out);
}